// Round 1
// baseline (682.397 us; speedup 1.0000x reference)
//
#include <hip/hip_runtime.h>
#include <hip/hip_bf16.h>
#include <math.h>

#define B_ 2
#define A_ 9
#define N_ 1024
#define P_ 4
#define D_ 256
#define H_ 8
#define DH_ 32
#define ROWS_ (B_*N_)   // 2048

// ---------------- prep: softmax(relu(kernels)) over A axis + 1/diag(degree) ----------------
__global__ void prep_kernel(const float* __restrict__ kernels, const float* __restrict__ degree,
                            float* __restrict__ soft, float* __restrict__ invd)
{
    int t = threadIdx.x;
    if (blockIdx.x == 0) {
        if (t < H_*P_) {
            int h = t >> 2, p = t & 3;
            float vals[A_];
            float m = 0.0f;   // relu outputs are >= 0
            #pragma unroll
            for (int a = 0; a < A_; a++) {
                float v = kernels[h*A_*P_ + a*P_ + p];
                v = v > 0.0f ? v : 0.0f;
                vals[a] = v;
                m = fmaxf(m, v);
            }
            float s = 0.0f;
            #pragma unroll
            for (int a = 0; a < A_; a++) { vals[a] = expf(vals[a] - m); s += vals[a]; }
            float inv = 1.0f / s;
            #pragma unroll
            for (int a = 0; a < A_; a++) soft[h*A_*P_ + a*P_ + p] = vals[a] * inv;
        }
    } else {
        int idx = (blockIdx.x - 1) * 256 + t;
        if (idx < ROWS_) {
            int b = idx >> 10, n = idx & (N_-1);
            invd[idx] = 1.0f / degree[(size_t)b*N_*N_ + (size_t)n*N_ + n];
        }
    }
}

// ---------------- chain: T_out = M_step @ T_in  (M mixed from adjacency in LDS) ----------------
// grid = B * (N/16) * 2 col-halves; 256 threads.
// Block covers 16 output rows x 128 cols (4 heads). LDS M: 4 planes of [16][32], plane stride 520
// floats (520%32==8 -> the 4 head planes land on different bank quads for the broadcast b128 reads).
__global__ void chain_kernel(const float* __restrict__ adj, const float* __restrict__ soft,
                             const float* __restrict__ Tin, float* __restrict__ Tout,
                             const float* __restrict__ invd, int step)
{
    __shared__ __align__(16) float Ms[4*520];
    __shared__ float soft_s[4][9];

    int bid = blockIdx.x;
    int half   = bid & 1;
    int rowblk = (bid >> 1) & 63;
    int b      = bid >> 7;
    int n0     = rowblk * 16;
    int tid    = threadIdx.x;

    if (tid < 36) {
        int hh = tid / 9, a = tid % 9;
        int h = half*4 + hh;
        soft_s[hh][a] = soft[h*A_*P_ + a*P_ + step];
    }
    __syncthreads();

    // compute-phase mapping: 256 threads = rsub(4) x hh(4) x e(16); 2 adjacent cols per thread
    int e    = tid & 15;
    int hh   = (tid >> 4) & 3;
    int rsub = tid >> 6;            // 0..3 -> rows rsub*4 .. rsub*4+3
    int head = half*4 + hh;
    int col  = head*32 + e*2;
    int rbase = rsub*4;

    // mixing-phase mapping: kk = tid&31, mr = tid>>5 (rows mr, mr+8)
    int mk = tid & 31;
    int mr = tid >> 5;

    float acc[4][2];
    #pragma unroll
    for (int r = 0; r < 4; r++) { acc[r][0] = 0.0f; acc[r][1] = 0.0f; }

    const float* adj_b = adj + (size_t)b*A_*N_*N_;
    const float* Tin_b = Tin + (size_t)b*N_*D_;

    for (int chunk = 0; chunk < N_/32; chunk++) {
        int m0 = chunk * 32;
        // ---- mix 4 head tiles [16][32] into LDS ----
        #pragma unroll
        for (int jr = 0; jr < 2; jr++) {
            int r = jr*8 + mr;
            float av[9];
            #pragma unroll
            for (int a = 0; a < A_; a++)
                av[a] = adj_b[((size_t)a*N_ + (n0+r))*N_ + m0 + mk];
            #pragma unroll
            for (int h4 = 0; h4 < 4; h4++) {
                float s = soft_s[h4][0]*av[0];
                #pragma unroll
                for (int a = 1; a < A_; a++) s += soft_s[h4][a]*av[a];
                Ms[h4*520 + r*32 + mk] = s;
            }
        }
        __syncthreads();
        // ---- accumulate: acc[r][c] += M[row][k] * T[k][col+c] ----
        #pragma unroll
        for (int k4 = 0; k4 < 8; k4++) {
            float2 t0 = *(const float2*)&Tin_b[(size_t)(m0 + k4*4 + 0)*D_ + col];
            float2 t1 = *(const float2*)&Tin_b[(size_t)(m0 + k4*4 + 1)*D_ + col];
            float2 t2 = *(const float2*)&Tin_b[(size_t)(m0 + k4*4 + 2)*D_ + col];
            float2 t3 = *(const float2*)&Tin_b[(size_t)(m0 + k4*4 + 3)*D_ + col];
            #pragma unroll
            for (int r = 0; r < 4; r++) {
                float4 m = *(const float4*)&Ms[hh*520 + (rbase + r)*32 + k4*4];
                acc[r][0] += m.x*t0.x + m.y*t1.x + m.z*t2.x + m.w*t3.x;
                acc[r][1] += m.x*t0.y + m.y*t1.y + m.z*t2.y + m.w*t3.y;
            }
        }
        __syncthreads();
    }

    #pragma unroll
    for (int r = 0; r < 4; r++) {
        int n = n0 + rbase + r;
        float scale = (step == 0) ? invd[b*N_ + n] : 1.0f;
        float2 o;
        o.x = acc[r][0]*scale;
        o.y = acc[r][1]*scale;
        *(float2*)&Tout[((size_t)b*N_ + n)*D_ + col] = o;
    }
}

// ---------------- generic 64x64-tile SIMT GEMM, 4x4 microtile ----------------
// MODE 0: C = A @ Wv(cat) + Bv     (B indexed via [H][D][DH], bias = Bv[H][N][DH])
// MODE 1: C = A @ B + add
// MODE 2: C = gelu_exact(A @ B + bias)
// MODE 3: C = A @ B + bias + add
#define BK 16
template<int MODE>
__global__ void gemm_kernel(const float* __restrict__ A, const float* __restrict__ Bm,
                            const float* __restrict__ bias, const float* __restrict__ add,
                            float* __restrict__ C, int M, int Ncols, int K)
{
    __shared__ __align__(16) float As[BK][68];
    __shared__ __align__(16) float Bs[BK][68];
    int m0 = blockIdx.x * 64;
    int n0 = blockIdx.y * 64;
    int tid = threadIdx.x;
    int tx = tid & 15, ty = tid >> 4;

    float acc[4][4];
    #pragma unroll
    for (int i = 0; i < 4; i++)
        #pragma unroll
        for (int j = 0; j < 4; j++) acc[i][j] = 0.0f;

    for (int k0 = 0; k0 < K; k0 += BK) {
        // stage A (transposed: As[k][m])
        {
            int m = tid >> 2;
            int k = (tid & 3) * 4;
            float4 v = *(const float4*)&A[(size_t)(m0+m)*K + k0 + k];
            As[k+0][m] = v.x; As[k+1][m] = v.y; As[k+2][m] = v.z; As[k+3][m] = v.w;
        }
        // stage B (Bs[k][n])
        {
            int k = tid >> 4;
            int n = (tid & 15) * 4;
            float4 v;
            if constexpr (MODE == 0) {
                int c = n0 + n; int h = c >> 5; int ee = c & 31;
                v = *(const float4*)&Bm[(size_t)h*D_*DH_ + (size_t)(k0+k)*DH_ + ee];
            } else {
                v = *(const float4*)&Bm[(size_t)(k0+k)*Ncols + n0 + n];
            }
            *(float4*)&Bs[k][n] = v;
        }
        __syncthreads();
        #pragma unroll
        for (int k = 0; k < BK; k++) {
            float4 a4 = *(const float4*)&As[k][ty*4];
            float4 b4 = *(const float4*)&Bs[k][tx*4];
            acc[0][0] += a4.x*b4.x; acc[0][1] += a4.x*b4.y; acc[0][2] += a4.x*b4.z; acc[0][3] += a4.x*b4.w;
            acc[1][0] += a4.y*b4.x; acc[1][1] += a4.y*b4.y; acc[1][2] += a4.y*b4.z; acc[1][3] += a4.y*b4.w;
            acc[2][0] += a4.z*b4.x; acc[2][1] += a4.z*b4.y; acc[2][2] += a4.z*b4.z; acc[2][3] += a4.z*b4.w;
            acc[3][0] += a4.w*b4.x; acc[3][1] += a4.w*b4.y; acc[3][2] += a4.w*b4.z; acc[3][3] += a4.w*b4.w;
        }
        __syncthreads();
    }

    #pragma unroll
    for (int i = 0; i < 4; i++) {
        int row  = m0 + ty*4 + i;
        int nloc = n0 + tx*4;
        float o[4];
        #pragma unroll
        for (int j = 0; j < 4; j++) {
            float v = acc[i][j];
            int c = nloc + j;
            if constexpr (MODE == 0) {
                int h = c >> 5, ee = c & 31, n = row & (N_-1);
                v += bias[(size_t)h*N_*DH_ + (size_t)n*DH_ + ee];
            }
            if constexpr (MODE == 1) {
                v += add[(size_t)row*Ncols + c];
            }
            if constexpr (MODE == 2) {
                v += bias[c];
                v = 0.5f * v * (1.0f + erff(v * 0.70710678118654752f));
            }
            if constexpr (MODE == 3) {
                v += bias[c] + add[(size_t)row*Ncols + c];
            }
            o[j] = v;
        }
        float4 ov = make_float4(o[0], o[1], o[2], o[3]);
        *(float4*)&C[(size_t)row*Ncols + nloc] = ov;
    }
}

// ---------------- layernorm over last dim W (256 or 512), one row per block ----------------
__global__ void ln_kernel(const float* __restrict__ in, float* __restrict__ out,
                          const float* __restrict__ g, const float* __restrict__ bta, int W)
{
    __shared__ float row[512];
    __shared__ float red[256];
    int r = blockIdx.x;
    int tid = threadIdx.x;
    const float* ip = in + (size_t)r * W;

    float local = 0.0f;
    for (int i = tid; i < W; i += 256) { float v = ip[i]; row[i] = v; local += v; }
    red[tid] = local;
    __syncthreads();
    for (int s = 128; s > 0; s >>= 1) {
        if (tid < s) red[tid] += red[tid + s];
        __syncthreads();
    }
    float mean = red[0] / (float)W;
    __syncthreads();

    float lv = 0.0f;
    for (int i = tid; i < W; i += 256) { float d = row[i] - mean; lv += d*d; }
    red[tid] = lv;
    __syncthreads();
    for (int s = 128; s > 0; s >>= 1) {
        if (tid < s) red[tid] += red[tid + s];
        __syncthreads();
    }
    float var = red[0] / (float)W;
    float rstd = 1.0f / sqrtf(var + 1e-12f);

    float* op = out + (size_t)r * W;
    for (int i = tid; i < W; i += 256) op[i] = (row[i] - mean) * rstd * g[i] + bta[i];
}

extern "C" void kernel_launch(void* const* d_in, const int* in_sizes, int n_in,
                              void* d_out, int out_size, void* d_ws, size_t ws_size,
                              hipStream_t stream)
{
    const float* adj    = (const float*)d_in[0];
    const float* degree = (const float*)d_in[1];
    const float* x      = (const float*)d_in[2];
    const float* kern   = (const float*)d_in[3];
    const float* Wv     = (const float*)d_in[4];
    const float* Bv     = (const float*)d_in[5];
    const float* W0     = (const float*)d_in[6];
    const float* gamma2 = (const float*)d_in[7];
    const float* beta2  = (const float*)d_in[8];
    const float* W1     = (const float*)d_in[9];
    const float* b1     = (const float*)d_in[10];
    const float* gf     = (const float*)d_in[11];
    const float* bf     = (const float*)d_in[12];
    const float* W2     = (const float*)d_in[13];
    const float* b2f    = (const float*)d_in[14];
    float* out = (float*)d_out;
    float* ws  = (float*)d_ws;

    float* soft  = ws;                       // 512
    float* invd  = ws + 512;                 // 2048
    float* T0    = ws + 2560;                // ROWS_*D_
    float* T1    = T0 + (size_t)ROWS_*D_;
    float* resid = T1 + (size_t)ROWS_*D_;
    float* hbuf  = resid + (size_t)ROWS_*D_;
    float* fbuf  = hbuf + (size_t)ROWS_*D_;      // ROWS_*2D
    float* fbuf2 = fbuf + (size_t)ROWS_*2*D_;    // ROWS_*2D

    // 1) soft weights + inverse degree diag
    prep_kernel<<<9, 256, 0, stream>>>(kern, degree, soft, invd);
    // 2) V = x @ Wv (+Bv), concat layout [B*N][256] col = h*32+e
    gemm_kernel<0><<<dim3(ROWS_/64, D_/64), 256, 0, stream>>>(x, Wv, Bv, nullptr, T0, ROWS_, D_, D_);
    // 3) chain right-to-left: T <- M_i @ T ; inv-degree scale on step 0
    int chain_grid = B_*(N_/16)*2;
    chain_kernel<<<chain_grid, 256, 0, stream>>>(adj, soft, T0, T1, invd, 3);
    chain_kernel<<<chain_grid, 256, 0, stream>>>(adj, soft, T1, T0, invd, 2);
    chain_kernel<<<chain_grid, 256, 0, stream>>>(adj, soft, T0, T1, invd, 1);
    chain_kernel<<<chain_grid, 256, 0, stream>>>(adj, soft, T1, T0, invd, 0);
    // 4) residual = attn @ W0 + x
    gemm_kernel<1><<<dim3(ROWS_/64, D_/64), 256, 0, stream>>>(T0, W0, nullptr, x, resid, ROWS_, D_, D_);
    // 5) h = LN(residual)
    ln_kernel<<<ROWS_, 256, 0, stream>>>(resid, hbuf, gamma2, beta2, D_);
    // 6) f = gelu(h @ W1 + b1)
    gemm_kernel<2><<<dim3(ROWS_/64, (2*D_)/64), 256, 0, stream>>>(hbuf, W1, b1, nullptr, fbuf, ROWS_, 2*D_, D_);
    // 7) f = LN(f)
    ln_kernel<<<ROWS_, 256, 0, stream>>>(fbuf, fbuf2, gf, bf, 2*D_);
    // 8) out = f @ W2 + b2f + residual
    gemm_kernel<3><<<dim3(ROWS_/64, D_/64), 256, 0, stream>>>(fbuf2, W2, b2f, resid, out, ROWS_, D_, 2*D_);
}

// Round 2
// 576.046 us; speedup vs baseline: 1.1846x; 1.1846x over previous
//
#include <hip/hip_runtime.h>
#include <hip/hip_bf16.h>
#include <math.h>

#define B_ 2
#define A_ 9
#define N_ 1024
#define P_ 4
#define D_ 256
#define H_ 8
#define DH_ 32
#define ROWS_ (B_*N_)   // 2048
#define KS_ 8           // K-split factor for chain
#define KSL_ (N_/KS_)   // 128 contraction elems per block

// ---------------- prep: softmax(relu(kernels)) over A axis + 1/diag(degree) ----------------
__global__ void prep_kernel(const float* __restrict__ kernels, const float* __restrict__ degree,
                            float* __restrict__ soft, float* __restrict__ invd)
{
    int t = threadIdx.x;
    if (blockIdx.x == 0) {
        if (t < H_*P_) {
            int h = t >> 2, p = t & 3;
            float vals[A_];
            float m = 0.0f;   // relu outputs are >= 0
            #pragma unroll
            for (int a = 0; a < A_; a++) {
                float v = kernels[h*A_*P_ + a*P_ + p];
                v = v > 0.0f ? v : 0.0f;
                vals[a] = v;
                m = fmaxf(m, v);
            }
            float s = 0.0f;
            #pragma unroll
            for (int a = 0; a < A_; a++) { vals[a] = expf(vals[a] - m); s += vals[a]; }
            float inv = 1.0f / s;
            #pragma unroll
            for (int a = 0; a < A_; a++) soft[h*A_*P_ + a*P_ + p] = vals[a] * inv;
        }
    } else {
        int idx = (blockIdx.x - 1) * 256 + t;
        if (idx < ROWS_) {
            int b = idx >> 10, n = idx & (N_-1);
            invd[idx] = 1.0f / degree[(size_t)b*N_*N_ + (size_t)n*N_ + n];
        }
    }
}

// ---------------- chain (K-split): partial[ks] = M_step[:, ks-slice] @ T_in[ks-slice, :] ----------
// grid = B * (N/16 rowblks) * 2 col-halves * KS_ ; 256 threads; 8 blocks/CU -> full occupancy.
__global__ __launch_bounds__(256, 8)
void chain_kernel(const float* __restrict__ adj, const float* __restrict__ soft,
                  const float* __restrict__ Tin, float* __restrict__ Pp, int step)
{
    __shared__ __align__(16) float Ms[4*520];
    __shared__ float soft_s[4][9];

    int bid    = blockIdx.x;
    int ks     = bid & (KS_-1);
    int half   = (bid >> 3) & 1;
    int rowblk = (bid >> 4) & 63;
    int b      = bid >> 10;
    int n0     = rowblk * 16;
    int tid    = threadIdx.x;

    if (tid < 36) {
        int hh = tid / 9, a = tid % 9;
        int h = half*4 + hh;
        soft_s[hh][a] = soft[h*A_*P_ + a*P_ + step];
    }
    __syncthreads();

    // compute-phase mapping: 256 threads = rsub(4) x hh(4) x e(16); 2 adjacent cols per thread
    int e    = tid & 15;
    int hh   = (tid >> 4) & 3;
    int rsub = tid >> 6;
    int head = half*4 + hh;
    int col  = head*32 + e*2;
    int rbase = rsub*4;

    // mixing-phase mapping
    int mk = tid & 31;
    int mr = tid >> 5;

    float acc[4][2];
    #pragma unroll
    for (int r = 0; r < 4; r++) { acc[r][0] = 0.0f; acc[r][1] = 0.0f; }

    const float* adj_b = adj + (size_t)b*A_*N_*N_;
    const float* Tin_b = Tin + (size_t)b*N_*D_;

    for (int chunk = 0; chunk < KSL_/32; chunk++) {
        int m0 = ks*KSL_ + chunk * 32;
        // ---- mix 4 head tiles [16][32] into LDS ----
        #pragma unroll
        for (int jr = 0; jr < 2; jr++) {
            int r = jr*8 + mr;
            float av[9];
            #pragma unroll
            for (int a = 0; a < A_; a++)
                av[a] = adj_b[((size_t)a*N_ + (n0+r))*N_ + m0 + mk];
            #pragma unroll
            for (int h4 = 0; h4 < 4; h4++) {
                float s = soft_s[h4][0]*av[0];
                #pragma unroll
                for (int a = 1; a < A_; a++) s += soft_s[h4][a]*av[a];
                Ms[h4*520 + r*32 + mk] = s;
            }
        }
        __syncthreads();
        // ---- accumulate ----
        #pragma unroll
        for (int k4 = 0; k4 < 8; k4++) {
            float2 t0 = *(const float2*)&Tin_b[(size_t)(m0 + k4*4 + 0)*D_ + col];
            float2 t1 = *(const float2*)&Tin_b[(size_t)(m0 + k4*4 + 1)*D_ + col];
            float2 t2 = *(const float2*)&Tin_b[(size_t)(m0 + k4*4 + 2)*D_ + col];
            float2 t3 = *(const float2*)&Tin_b[(size_t)(m0 + k4*4 + 3)*D_ + col];
            #pragma unroll
            for (int r = 0; r < 4; r++) {
                float4 m = *(const float4*)&Ms[hh*520 + (rbase + r)*32 + k4*4];
                acc[r][0] += m.x*t0.x + m.y*t1.x + m.z*t2.x + m.w*t3.x;
                acc[r][1] += m.x*t0.y + m.y*t1.y + m.z*t2.y + m.w*t3.y;
            }
        }
        __syncthreads();
    }

    #pragma unroll
    for (int r = 0; r < 4; r++) {
        int n = n0 + rbase + r;
        float2 o;
        o.x = acc[r][0];
        o.y = acc[r][1];
        *(float2*)&Pp[((size_t)ks*ROWS_ + (size_t)b*N_ + n)*D_ + col] = o;
    }
}

// ---------------- reduce the KS_ partial slabs; apply inv-degree scale on step 0 -------------
__global__ void chain_reduce(const float* __restrict__ Pp, float* __restrict__ Tout,
                             const float* __restrict__ invd, int step)
{
    int idx = blockIdx.x * 256 + threadIdx.x;      // one float4 per thread
    int row = idx / (D_/4);
    int c4  = (idx % (D_/4)) * 4;
    float4 s = make_float4(0.f, 0.f, 0.f, 0.f);
    #pragma unroll
    for (int ks = 0; ks < KS_; ks++) {
        float4 v = *(const float4*)&Pp[((size_t)ks*ROWS_ + row)*D_ + c4];
        s.x += v.x; s.y += v.y; s.z += v.z; s.w += v.w;
    }
    float scale = (step == 0) ? invd[row] : 1.0f;
    s.x *= scale; s.y *= scale; s.z *= scale; s.w *= scale;
    *(float4*)&Tout[(size_t)row*D_ + c4] = s;
}

// ---------------- generic 64x64-tile SIMT GEMM, 4x4 microtile ----------------
// MODE 0: C = A @ Wv(cat) + Bv     MODE 1: C = A @ B + add
// MODE 2: C = gelu_exact(A @ B + bias)   MODE 3: C = A @ B + bias + add
#define BK 16
template<int MODE>
__global__ void gemm_kernel(const float* __restrict__ A, const float* __restrict__ Bm,
                            const float* __restrict__ bias, const float* __restrict__ add,
                            float* __restrict__ C, int M, int Ncols, int K)
{
    __shared__ __align__(16) float As[BK][68];
    __shared__ __align__(16) float Bs[BK][68];
    int m0 = blockIdx.x * 64;
    int n0 = blockIdx.y * 64;
    int tid = threadIdx.x;
    int tx = tid & 15, ty = tid >> 4;

    float acc[4][4];
    #pragma unroll
    for (int i = 0; i < 4; i++)
        #pragma unroll
        for (int j = 0; j < 4; j++) acc[i][j] = 0.0f;

    for (int k0 = 0; k0 < K; k0 += BK) {
        {
            int m = tid >> 2;
            int k = (tid & 3) * 4;
            float4 v = *(const float4*)&A[(size_t)(m0+m)*K + k0 + k];
            As[k+0][m] = v.x; As[k+1][m] = v.y; As[k+2][m] = v.z; As[k+3][m] = v.w;
        }
        {
            int k = tid >> 4;
            int n = (tid & 15) * 4;
            float4 v;
            if constexpr (MODE == 0) {
                int c = n0 + n; int h = c >> 5; int ee = c & 31;
                v = *(const float4*)&Bm[(size_t)h*D_*DH_ + (size_t)(k0+k)*DH_ + ee];
            } else {
                v = *(const float4*)&Bm[(size_t)(k0+k)*Ncols + n0 + n];
            }
            *(float4*)&Bs[k][n] = v;
        }
        __syncthreads();
        #pragma unroll
        for (int k = 0; k < BK; k++) {
            float4 a4 = *(const float4*)&As[k][ty*4];
            float4 b4 = *(const float4*)&Bs[k][tx*4];
            acc[0][0] += a4.x*b4.x; acc[0][1] += a4.x*b4.y; acc[0][2] += a4.x*b4.z; acc[0][3] += a4.x*b4.w;
            acc[1][0] += a4.y*b4.x; acc[1][1] += a4.y*b4.y; acc[1][2] += a4.y*b4.z; acc[1][3] += a4.y*b4.w;
            acc[2][0] += a4.z*b4.x; acc[2][1] += a4.z*b4.y; acc[2][2] += a4.z*b4.z; acc[2][3] += a4.z*b4.w;
            acc[3][0] += a4.w*b4.x; acc[3][1] += a4.w*b4.y; acc[3][2] += a4.w*b4.z; acc[3][3] += a4.w*b4.w;
        }
        __syncthreads();
    }

    #pragma unroll
    for (int i = 0; i < 4; i++) {
        int row  = m0 + ty*4 + i;
        int nloc = n0 + tx*4;
        float o[4];
        #pragma unroll
        for (int j = 0; j < 4; j++) {
            float v = acc[i][j];
            int c = nloc + j;
            if constexpr (MODE == 0) {
                int h = c >> 5, ee = c & 31, n = row & (N_-1);
                v += bias[(size_t)h*N_*DH_ + (size_t)n*DH_ + ee];
            }
            if constexpr (MODE == 1) {
                v += add[(size_t)row*Ncols + c];
            }
            if constexpr (MODE == 2) {
                v += bias[c];
                v = 0.5f * v * (1.0f + erff(v * 0.70710678118654752f));
            }
            if constexpr (MODE == 3) {
                v += bias[c] + add[(size_t)row*Ncols + c];
            }
            o[j] = v;
        }
        float4 ov = make_float4(o[0], o[1], o[2], o[3]);
        *(float4*)&C[(size_t)row*Ncols + nloc] = ov;
    }
}

// ---------------- layernorm over last dim W (256 or 512), one row per block ----------------
__global__ void ln_kernel(const float* __restrict__ in, float* __restrict__ out,
                          const float* __restrict__ g, const float* __restrict__ bta, int W)
{
    __shared__ float row[512];
    __shared__ float red[256];
    int r = blockIdx.x;
    int tid = threadIdx.x;
    const float* ip = in + (size_t)r * W;

    float local = 0.0f;
    for (int i = tid; i < W; i += 256) { float v = ip[i]; row[i] = v; local += v; }
    red[tid] = local;
    __syncthreads();
    for (int s = 128; s > 0; s >>= 1) {
        if (tid < s) red[tid] += red[tid + s];
        __syncthreads();
    }
    float mean = red[0] / (float)W;
    __syncthreads();

    float lv = 0.0f;
    for (int i = tid; i < W; i += 256) { float d = row[i] - mean; lv += d*d; }
    red[tid] = lv;
    __syncthreads();
    for (int s = 128; s > 0; s >>= 1) {
        if (tid < s) red[tid] += red[tid + s];
        __syncthreads();
    }
    float var = red[0] / (float)W;
    float rstd = 1.0f / sqrtf(var + 1e-12f);

    float* op = out + (size_t)r * W;
    for (int i = tid; i < W; i += 256) op[i] = (row[i] - mean) * rstd * g[i] + bta[i];
}

extern "C" void kernel_launch(void* const* d_in, const int* in_sizes, int n_in,
                              void* d_out, int out_size, void* d_ws, size_t ws_size,
                              hipStream_t stream)
{
    const float* adj    = (const float*)d_in[0];
    const float* degree = (const float*)d_in[1];
    const float* x      = (const float*)d_in[2];
    const float* kern   = (const float*)d_in[3];
    const float* Wv     = (const float*)d_in[4];
    const float* Bv     = (const float*)d_in[5];
    const float* W0     = (const float*)d_in[6];
    const float* gamma2 = (const float*)d_in[7];
    const float* beta2  = (const float*)d_in[8];
    const float* W1     = (const float*)d_in[9];
    const float* b1     = (const float*)d_in[10];
    const float* gf     = (const float*)d_in[11];
    const float* bf     = (const float*)d_in[12];
    const float* W2     = (const float*)d_in[13];
    const float* b2f    = (const float*)d_in[14];
    float* out = (float*)d_out;
    float* ws  = (float*)d_ws;

    float* soft  = ws;                           // 512
    float* invd  = ws + 512;                     // 2048
    float* T0    = ws + 2560;                    // ROWS_*D_
    float* T1    = T0 + (size_t)ROWS_*D_;
    float* Pp    = T1 + (size_t)ROWS_*D_;        // KS_*ROWS_*D_  (16 MB)
    float* resid = Pp + (size_t)KS_*ROWS_*D_;
    float* hbuf  = resid + (size_t)ROWS_*D_;
    float* fbuf  = hbuf + (size_t)ROWS_*D_;      // ROWS_*2D
    float* fbuf2 = fbuf + (size_t)ROWS_*2*D_;    // ROWS_*2D

    // 1) soft weights + inverse degree diag
    prep_kernel<<<9, 256, 0, stream>>>(kern, degree, soft, invd);
    // 2) V = x @ Wv (+Bv), concat layout [B*N][256] col = h*32+e
    gemm_kernel<0><<<dim3(ROWS_/64, D_/64), 256, 0, stream>>>(x, Wv, Bv, nullptr, T0, ROWS_, D_, D_);
    // 3) chain right-to-left with K-split partials + reduce; inv-degree scale on step 0
    int chain_grid  = B_*(N_/16)*2*KS_;              // 2048
    int reduce_grid = (ROWS_*D_/4) / 256;            // 512
    chain_kernel<<<chain_grid, 256, 0, stream>>>(adj, soft, T0, Pp, 3);
    chain_reduce<<<reduce_grid, 256, 0, stream>>>(Pp, T1, invd, 3);
    chain_kernel<<<chain_grid, 256, 0, stream>>>(adj, soft, T1, Pp, 2);
    chain_reduce<<<reduce_grid, 256, 0, stream>>>(Pp, T0, invd, 2);
    chain_kernel<<<chain_grid, 256, 0, stream>>>(adj, soft, T0, Pp, 1);
    chain_reduce<<<reduce_grid, 256, 0, stream>>>(Pp, T1, invd, 1);
    chain_kernel<<<chain_grid, 256, 0, stream>>>(adj, soft, T1, Pp, 0);
    chain_reduce<<<reduce_grid, 256, 0, stream>>>(Pp, T0, invd, 0);
    // 4) residual = attn @ W0 + x
    gemm_kernel<1><<<dim3(ROWS_/64, D_/64), 256, 0, stream>>>(T0, W0, nullptr, x, resid, ROWS_, D_, D_);
    // 5) h = LN(residual)
    ln_kernel<<<ROWS_, 256, 0, stream>>>(resid, hbuf, gamma2, beta2, D_);
    // 6) f = gelu(h @ W1 + b1)
    gemm_kernel<2><<<dim3(ROWS_/64, (2*D_)/64), 256, 0, stream>>>(hbuf, W1, b1, nullptr, fbuf, ROWS_, 2*D_, D_);
    // 7) f = LN(f)
    ln_kernel<<<ROWS_, 256, 0, stream>>>(fbuf, fbuf2, gf, bf, 2*D_);
    // 8) out = f @ W2 + b2f + residual
    gemm_kernel<3><<<dim3(ROWS_/64, D_/64), 256, 0, stream>>>(fbuf2, W2, b2f, resid, out, ROWS_, D_, 2*D_);
}